// Round 10
// baseline (162.260 us; speedup 1.0000x reference)
//
#include <hip/hip_runtime.h>
#include <hip/hip_bf16.h>
#include <cstdint>

// Problem constants (features: [512, 16, 512] fp32 -> N=8192 rows, D=512)
#define N_TOT 8192
#define DDIM  512
#define DBYTES 512                     // bytes per row in fp8
#define NBLK  64                       // 8192 / 128 tile blocks per dim
#define NTRI  (NBLK * (NBLK + 1) / 2)  // 2080 lower-triangle blocks
constexpr float INV_T = 1.0f / 0.07f;

typedef uint8_t u8;
typedef __attribute__((ext_vector_type(8))) int i32x8_t;
typedef __attribute__((ext_vector_type(4))) float f32x4_t;

// ---- kernel 1: row-normalize fp32 -> fp8 e4m3 (+ zero tsum and out) --------
__global__ __launch_bounds__(256) void normalize_kernel(const float* __restrict__ X,
                                                        u8* __restrict__ Xn,
                                                        float* __restrict__ tsum,
                                                        float* __restrict__ out) {
  if (blockIdx.x < 32) tsum[blockIdx.x * 256 + threadIdx.x] = 0.0f;
  if (blockIdx.x == 32 && threadIdx.x == 0) out[0] = 0.0f;
  const int lane = threadIdx.x & 63;
  const int row  = blockIdx.x * 4 + (threadIdx.x >> 6);
  const float4* xr = (const float4*)(X + (size_t)row * DDIM);
  float4 v0 = xr[lane];
  float4 v1 = xr[lane + 64];
  float s = v0.x * v0.x + v0.y * v0.y + v0.z * v0.z + v0.w * v0.w
          + v1.x * v1.x + v1.y * v1.y + v1.z * v1.z + v1.w * v1.w;
#pragma unroll
  for (int m = 1; m < 64; m <<= 1) s += __shfl_xor(s, m);
  const float scale = 1.0f / fmaxf(sqrtf(s), 1e-8f);
  int w0 = __builtin_amdgcn_cvt_pk_fp8_f32(v0.x * scale, v0.y * scale, 0, 0);
  w0     = __builtin_amdgcn_cvt_pk_fp8_f32(v0.z * scale, v0.w * scale, w0, 1);
  int w1 = __builtin_amdgcn_cvt_pk_fp8_f32(v1.x * scale, v1.y * scale, 0, 0);
  w1     = __builtin_amdgcn_cvt_pk_fp8_f32(v1.z * scale, v1.w * scale, w1, 1);
  uint32_t* orow = (uint32_t*)(Xn + (size_t)row * DBYTES);
  orow[lane]      = (uint32_t)w0;
  orow[lane + 64] = (uint32_t)w1;
}

// ---- kernel 2: lower-triangle tiles of C = Xn*Xn^T, fused exp row/col sums -
// fp8 path: 128x128 tile, BK=128 bytes (4 K-iters), 256 threads = 4 waves in
// 2x2; mfma_scale 16x16x128 f8f6f4 (e4m3, unit E8M0 scales). REGISTER-STAGED
// pipeline: tile k+1 is loaded global->VGPR (issued before the MFMAs of tile
// k, lands during compute) and committed to the single 32 KB LDS buffer via
// ds_write_b128 between two lgkm-only barriers. No barrier ever drains
// vmcnt-to-HBM (R7's 4x ~1300 cyc drains -> ~0; R5/R8 lessons: keep LDS at
// 32 KB, keep B in LDS). NO device-scope fences (R3: L2 wb/inv -> 3x).
// LDS XOR swizzle (R2-verified conflict-free frag reads): granule (row, j)
// j=0..7 (16B) stored at slot row*8 + (j ^ (row&7)); the global source
// address inverts the swizzle.
__global__ __launch_bounds__(256, 3) void gemm_exp_rowsum(const u8* __restrict__ Xn,
                                                          float* __restrict__ tsum) {
  __shared__ __align__(16) u8 sA[128 * 128];  // 16 KB
  __shared__ __align__(16) u8 sB[128 * 128];  // 16 KB

  // triangular decode: blockIdx.x -> (bi >= bj)
  const int k = blockIdx.x;
  int bi = (int)((sqrtf(8.0f * (float)k + 1.0f) - 1.0f) * 0.5f);
  while ((bi + 1) * (bi + 2) / 2 <= k) ++bi;
  while (bi * (bi + 1) / 2 > k) --bi;
  const int bj = k - bi * (bi + 1) / 2;
  const int rowBase = bi * 128;
  const int colBase = bj * 128;
  const bool isDiag = (bi == bj);

  const int t    = threadIdx.x;   // 0..255
  const int lane = t & 63;
  const int l15  = lane & 15;
  const int quad = lane >> 4;
  const int w    = t >> 6;        // 0..3
  const int wm   = w >> 1;        // 0..1: row offset wm*64
  const int wn   = w & 1;         // 0..1: col offset wn*64

  f32x4_t acc[4][4];
#pragma unroll
  for (int i = 0; i < 4; i++)
#pragma unroll
    for (int j = 0; j < 4; j++) acc[i][j] = {0.f, 0.f, 0.f, 0.f};

  // staging map (R7-identical): per panel 1024 granules of 16B (128 rows x 8);
  // thread t handles granules t, t+256, t+512, t+768 -> rows srow+{0,32,64,96}
  // at the same swizzle-inverted byte offset goff ((srow+32)&7 == srow&7).
  const int srow = t >> 3;
  const int goff = ((t & 7) ^ (srow & 7)) * 16;
  const u8* gA = Xn + (size_t)(rowBase + srow) * DBYTES + goff;
  const u8* gB = Xn + (size_t)(colBase + srow) * DBYTES + goff;
  u8* lA = sA + t * 16;
  u8* lB = sB + t * 16;

  int4 vA[4], vB[4];
  // prologue: tile 0 global->reg, reg->LDS, one lgkm barrier
#pragma unroll
  for (int r = 0; r < 4; r++) {
    vA[r] = *(const int4*)(gA + (size_t)(r * 32) * DBYTES);
    vB[r] = *(const int4*)(gB + (size_t)(r * 32) * DBYTES);
  }
#pragma unroll
  for (int r = 0; r < 4; r++) {
    *(int4*)(lA + r * 4096) = vA[r];
    *(int4*)(lB + r * 4096) = vB[r];
  }
  __syncthreads();

#pragma unroll
  for (int it = 0; it < 4; ++it) {
    // fragment reads for tile `it` (conflict-free swizzled ds_read_b128)
    i32x8_t a[4], b[4];
#pragma unroll
    for (int mi = 0; mi < 4; mi++) {
      const int row = wm * 64 + mi * 16 + l15;
      const int s0 = (((quad * 2) ^ (row & 7)) * 16);
      const int s1 = (((quad * 2 + 1) ^ (row & 7)) * 16);
      int4 lo = *(const int4*)&sA[row * 128 + s0];
      int4 hi = *(const int4*)&sA[row * 128 + s1];
      a[mi] = (i32x8_t){lo.x, lo.y, lo.z, lo.w, hi.x, hi.y, hi.z, hi.w};
    }
#pragma unroll
    for (int ni = 0; ni < 4; ni++) {
      const int row = wn * 64 + ni * 16 + l15;
      const int s0 = (((quad * 2) ^ (row & 7)) * 16);
      const int s1 = (((quad * 2 + 1) ^ (row & 7)) * 16);
      int4 lo = *(const int4*)&sB[row * 128 + s0];
      int4 hi = *(const int4*)&sB[row * 128 + s1];
      b[ni] = (i32x8_t){lo.x, lo.y, lo.z, lo.w, hi.x, hi.y, hi.z, hi.w};
    }

    // issue next tile's global loads NOW -- they land during the MFMA phase
    if (it < 3) {
      const int k0 = (it + 1) * 128;
#pragma unroll
      for (int r = 0; r < 4; r++) {
        vA[r] = *(const int4*)(gA + (size_t)(r * 32) * DBYTES + k0);
        vB[r] = *(const int4*)(gB + (size_t)(r * 32) * DBYTES + k0);
      }
    }

#pragma unroll
    for (int mi = 0; mi < 4; mi++)
#pragma unroll
      for (int ni = 0; ni < 4; ni++)
        acc[mi][ni] = __builtin_amdgcn_mfma_scale_f32_16x16x128_f8f6f4(
            a[mi], b[ni], acc[mi][ni], 0, 0, 0, 0x7F7F7F7Fu, 0, 0x7F7F7F7Fu);

    if (it < 3) {
      __syncthreads();  // all waves done reading tile `it` (lgkm-only drain)
#pragma unroll
      for (int r = 0; r < 4; r++) {
        *(int4*)(lA + r * 4096) = vA[r];
        *(int4*)(lB + r * 4096) = vB[r];
      }
      __syncthreads();  // tile `it+1` visible (lgkm-only drain)
    }
  }

  // epilogue: e = exp((c-1)/T). C/D layout: col = lane&15, row = quad*4 + reg
  // (shape-determined, dtype-independent -- m121..m128).
  if (isDiag) {
#pragma unroll
    for (int mi = 0; mi < 4; mi++) {
#pragma unroll
      for (int r = 0; r < 4; r++) {
        const int row = rowBase + wm * 64 + mi * 16 + quad * 4 + r;
        float rs = 0.0f;
#pragma unroll
        for (int ni = 0; ni < 4; ni++) {
          const int col = colBase + wn * 64 + ni * 16 + l15;
          const float e = __expf((acc[mi][ni][r] - 1.0f) * INV_T);
          rs += (row == col) ? 0.0f : e;
        }
        rs += __shfl_xor(rs, 1);
        rs += __shfl_xor(rs, 2);
        rs += __shfl_xor(rs, 4);
        rs += __shfl_xor(rs, 8);
        if (l15 == 0) atomicAdd(&tsum[row], rs);
      }
    }
  } else {
    float csum[4] = {0.f, 0.f, 0.f, 0.f};
#pragma unroll
    for (int mi = 0; mi < 4; mi++) {
#pragma unroll
      for (int r = 0; r < 4; r++) {
        const int row = rowBase + wm * 64 + mi * 16 + quad * 4 + r;
        float rs = 0.0f;
#pragma unroll
        for (int ni = 0; ni < 4; ni++) {
          const float e = __expf((acc[mi][ni][r] - 1.0f) * INV_T);
          rs += e;
          csum[ni] += e;
        }
        rs += __shfl_xor(rs, 1);
        rs += __shfl_xor(rs, 2);
        rs += __shfl_xor(rs, 4);
        rs += __shfl_xor(rs, 8);
        if (l15 == 0) atomicAdd(&tsum[row], rs);
      }
    }
#pragma unroll
    for (int ni = 0; ni < 4; ni++) {
      csum[ni] += __shfl_xor(csum[ni], 16);
      csum[ni] += __shfl_xor(csum[ni], 32);
      if (quad == 0) atomicAdd(&tsum[colBase + wn * 64 + ni * 16 + l15], csum[ni]);
    }
  }
}

// ---- kernel 3: loss = mean_i log1p(t_i), 32 blocks + atomic accumulate -----
__global__ __launch_bounds__(256) void finalize_kernel(const float* __restrict__ tsum,
                                                       float* __restrict__ out) {
  const int i = blockIdx.x * 256 + threadIdx.x;
  float s = log1pf(tsum[i]);
#pragma unroll
  for (int m = 1; m < 64; m <<= 1) s += __shfl_xor(s, m);
  __shared__ float ws[4];
  if ((threadIdx.x & 63) == 0) ws[threadIdx.x >> 6] = s;
  __syncthreads();
  if (threadIdx.x == 0)
    atomicAdd(out, (ws[0] + ws[1] + ws[2] + ws[3]) * (1.0f / N_TOT));
}

// ---- launcher --------------------------------------------------------------
extern "C" void kernel_launch(void* const* d_in, const int* in_sizes, int n_in,
                              void* d_out, int out_size, void* d_ws, size_t ws_size,
                              hipStream_t stream) {
  const float* X = (const float*)d_in[0];
  float* out = (float*)d_out;

  float* tsum = (float*)d_ws;                       // 8192 fp32 = 32 KB
  u8* Xn = (u8*)d_ws + 65536;                       // 8192x512 fp8 = 4 MB

  normalize_kernel<<<N_TOT / 4, 256, 0, stream>>>(X, Xn, tsum, out);
  gemm_exp_rowsum<<<NTRI, 256, 0, stream>>>(Xn, tsum);
  finalize_kernel<<<N_TOT / 256, 256, 0, stream>>>(tsum, out);
}

// Round 11
// 121.657 us; speedup vs baseline: 1.3338x; 1.3338x over previous
//
#include <hip/hip_runtime.h>
#include <hip/hip_bf16.h>
#include <cstdint>

// Problem constants (features: [512, 16, 512] fp32 -> N=8192 rows, D=512)
#define N_TOT 8192
#define DDIM  512
#define DBYTES 512                     // bytes per row in fp8
#define NBLK  64                       // 8192 / 128 tile blocks per dim
#define NTRI  (NBLK * (NBLK + 1) / 2)  // 2080 lower-triangle blocks
constexpr float INV_T = 1.0f / 0.07f;

typedef uint8_t u8;
typedef __attribute__((ext_vector_type(8))) int i32x8_t;
typedef __attribute__((ext_vector_type(4))) float f32x4_t;

// ---- helpers ---------------------------------------------------------------

// async 16B global->LDS (global_load_lds_dwordx4). LDS dst is wave-uniform
// base + lane*16 (lane-contiguous) -- swizzle is applied to the GLOBAL src.
__device__ __forceinline__ void load16_to_lds(const void* g, void* l) {
  __builtin_amdgcn_global_load_lds(
      (const __attribute__((address_space(1))) unsigned int*)g,
      (__attribute__((address_space(3))) unsigned int*)l, 16, 0, 0);
}

// ---- kernel 1: row-normalize fp32 -> fp8 e4m3 (+ zero tsum and out) --------
__global__ __launch_bounds__(256) void normalize_kernel(const float* __restrict__ X,
                                                        u8* __restrict__ Xn,
                                                        float* __restrict__ tsum,
                                                        float* __restrict__ out) {
  if (blockIdx.x < 32) tsum[blockIdx.x * 256 + threadIdx.x] = 0.0f;
  if (blockIdx.x == 32 && threadIdx.x == 0) out[0] = 0.0f;
  const int lane = threadIdx.x & 63;
  const int row  = blockIdx.x * 4 + (threadIdx.x >> 6);
  const float4* xr = (const float4*)(X + (size_t)row * DDIM);
  float4 v0 = xr[lane];
  float4 v1 = xr[lane + 64];
  float s = v0.x * v0.x + v0.y * v0.y + v0.z * v0.z + v0.w * v0.w
          + v1.x * v1.x + v1.y * v1.y + v1.z * v1.z + v1.w * v1.w;
#pragma unroll
  for (int m = 1; m < 64; m <<= 1) s += __shfl_xor(s, m);
  const float scale = 1.0f / fmaxf(sqrtf(s), 1e-8f);
  int w0 = __builtin_amdgcn_cvt_pk_fp8_f32(v0.x * scale, v0.y * scale, 0, 0);
  w0     = __builtin_amdgcn_cvt_pk_fp8_f32(v0.z * scale, v0.w * scale, w0, 1);
  int w1 = __builtin_amdgcn_cvt_pk_fp8_f32(v1.x * scale, v1.y * scale, 0, 0);
  w1     = __builtin_amdgcn_cvt_pk_fp8_f32(v1.z * scale, v1.w * scale, w1, 1);
  uint32_t* orow = (uint32_t*)(Xn + (size_t)row * DBYTES);
  orow[lane]      = (uint32_t)w0;
  orow[lane + 64] = (uint32_t)w1;
}

// ---- kernel 2: lower-triangle tiles of C = Xn*Xn^T, fused exp row/col sums -
// fp8 path: 128x128 tile, BK=256 bytes -> only TWO K-iters (two vmcnt(0)
// barrier drains per block, down from R7's four -- the drain count is the
// measured cost knob: R6->R7 8->4 drains gained 15 us). 256 threads = 4 waves
// in 2x2; mfma_scale 16x16x128 f8f6f4 (e4m3, unit E8M0 scales), 2 kk sub-
// steps per iter. Single-buffered 64 KB LDS -> 2 blocks/CU (matches measured
// effective co-residency; R5/R8: bigger LDS or no-LDS both regressed).
// Staging via global_load_lds only (R9: register-staging spills to scratch).
// NO device-scope fences (R3: L2 wb/inv -> 3x).
// LDS XOR swizzle within each 8-granule (128 B) half-row chunk: granule
// (row, j) j=0..15 stored at slot (j&8) | ((j&7) ^ (row&7)); global source
// address inverts the swizzle -> frag ds_read_b128 conflict-free (R2-family).
__global__ __launch_bounds__(256, 2) void gemm_exp_rowsum(const u8* __restrict__ Xn,
                                                          float* __restrict__ tsum) {
  __shared__ __align__(16) u8 sA[128 * 256];  // 32 KB
  __shared__ __align__(16) u8 sB[128 * 256];  // 32 KB

  // triangular decode: blockIdx.x -> (bi >= bj)
  const int k = blockIdx.x;
  int bi = (int)((sqrtf(8.0f * (float)k + 1.0f) - 1.0f) * 0.5f);
  while ((bi + 1) * (bi + 2) / 2 <= k) ++bi;
  while (bi * (bi + 1) / 2 > k) --bi;
  const int bj = k - bi * (bi + 1) / 2;
  const int rowBase = bi * 128;
  const int colBase = bj * 128;
  const bool isDiag = (bi == bj);

  const int t    = threadIdx.x;   // 0..255
  const int lane = t & 63;
  const int l15  = lane & 15;
  const int quad = lane >> 4;
  const int w    = t >> 6;        // 0..3
  const int wm   = w >> 1;        // 0..1: row offset wm*64
  const int wn   = w & 1;         // 0..1: col offset wn*64

  f32x4_t acc[4][4];
#pragma unroll
  for (int i = 0; i < 4; i++)
#pragma unroll
    for (int j = 0; j < 4; j++) acc[i][j] = {0.f, 0.f, 0.f, 0.f};

  // staging map: per panel-iter 2048 granules of 16B (128 rows x 16).
  // granule g: row=g>>4, j=g&15. thread t handles g = t + i*256 (i=0..7)
  // -> row = (t>>4) + 16*i (row&7 invariant), j = t&15 invariant.
  // physical slot j stores logical granule jl = (j&8) | ((j&7)^(row&7)).
  const int srow = t >> 4;
  const int jj   = t & 15;
  const int jl   = (jj & 8) | ((jj & 7) ^ (srow & 7));
  const u8* gA = Xn + (size_t)(rowBase + srow) * DBYTES + jl * 16;
  const u8* gB = Xn + (size_t)(colBase + srow) * DBYTES + jl * 16;
  u8* lA = sA + t * 16;
  u8* lB = sB + t * 16;

  for (int k0 = 0; k0 < DBYTES; k0 += 256) {  // 2 iters
#pragma unroll
    for (int i = 0; i < 8; i++) {
      load16_to_lds(gA + (size_t)(i * 16) * DBYTES + k0, lA + i * 4096);
      load16_to_lds(gB + (size_t)(i * 16) * DBYTES + k0, lB + i * 4096);
    }
    __syncthreads();

#pragma unroll
    for (int kk = 0; kk < 2; kk++) {
      i32x8_t a[4], b[4];
#pragma unroll
      for (int mi = 0; mi < 4; mi++) {
        const int row = wm * 64 + mi * 16 + l15;
        const int s0 = row * 256 + (kk * 8 + ((quad * 2) ^ (row & 7))) * 16;
        const int s1 = row * 256 + (kk * 8 + ((quad * 2 + 1) ^ (row & 7))) * 16;
        int4 lo = *(const int4*)&sA[s0];
        int4 hi = *(const int4*)&sA[s1];
        a[mi] = (i32x8_t){lo.x, lo.y, lo.z, lo.w, hi.x, hi.y, hi.z, hi.w};
      }
#pragma unroll
      for (int ni = 0; ni < 4; ni++) {
        const int row = wn * 64 + ni * 16 + l15;
        const int s0 = row * 256 + (kk * 8 + ((quad * 2) ^ (row & 7))) * 16;
        const int s1 = row * 256 + (kk * 8 + ((quad * 2 + 1) ^ (row & 7))) * 16;
        int4 lo = *(const int4*)&sB[s0];
        int4 hi = *(const int4*)&sB[s1];
        b[ni] = (i32x8_t){lo.x, lo.y, lo.z, lo.w, hi.x, hi.y, hi.z, hi.w};
      }
#pragma unroll
      for (int mi = 0; mi < 4; mi++)
#pragma unroll
        for (int ni = 0; ni < 4; ni++)
          acc[mi][ni] = __builtin_amdgcn_mfma_scale_f32_16x16x128_f8f6f4(
              a[mi], b[ni], acc[mi][ni], 0, 0, 0, 0x7F7F7F7Fu, 0, 0x7F7F7F7Fu);
    }
    __syncthreads();
  }

  // epilogue: e = exp((c-1)/T). C/D layout: col = lane&15, row = quad*4 + reg
  // (shape-determined, dtype-independent -- m121..m128).
  if (isDiag) {
#pragma unroll
    for (int mi = 0; mi < 4; mi++) {
#pragma unroll
      for (int r = 0; r < 4; r++) {
        const int row = rowBase + wm * 64 + mi * 16 + quad * 4 + r;
        float rs = 0.0f;
#pragma unroll
        for (int ni = 0; ni < 4; ni++) {
          const int col = colBase + wn * 64 + ni * 16 + l15;
          const float e = __expf((acc[mi][ni][r] - 1.0f) * INV_T);
          rs += (row == col) ? 0.0f : e;
        }
        rs += __shfl_xor(rs, 1);
        rs += __shfl_xor(rs, 2);
        rs += __shfl_xor(rs, 4);
        rs += __shfl_xor(rs, 8);
        if (l15 == 0) atomicAdd(&tsum[row], rs);
      }
    }
  } else {
    float csum[4] = {0.f, 0.f, 0.f, 0.f};
#pragma unroll
    for (int mi = 0; mi < 4; mi++) {
#pragma unroll
      for (int r = 0; r < 4; r++) {
        const int row = rowBase + wm * 64 + mi * 16 + quad * 4 + r;
        float rs = 0.0f;
#pragma unroll
        for (int ni = 0; ni < 4; ni++) {
          const float e = __expf((acc[mi][ni][r] - 1.0f) * INV_T);
          rs += e;
          csum[ni] += e;
        }
        rs += __shfl_xor(rs, 1);
        rs += __shfl_xor(rs, 2);
        rs += __shfl_xor(rs, 4);
        rs += __shfl_xor(rs, 8);
        if (l15 == 0) atomicAdd(&tsum[row], rs);
      }
    }
#pragma unroll
    for (int ni = 0; ni < 4; ni++) {
      csum[ni] += __shfl_xor(csum[ni], 16);
      csum[ni] += __shfl_xor(csum[ni], 32);
      if (quad == 0) atomicAdd(&tsum[colBase + wn * 64 + ni * 16 + l15], csum[ni]);
    }
  }
}

// ---- kernel 3: loss = mean_i log1p(t_i), 32 blocks + atomic accumulate -----
__global__ __launch_bounds__(256) void finalize_kernel(const float* __restrict__ tsum,
                                                       float* __restrict__ out) {
  const int i = blockIdx.x * 256 + threadIdx.x;
  float s = log1pf(tsum[i]);
#pragma unroll
  for (int m = 1; m < 64; m <<= 1) s += __shfl_xor(s, m);
  __shared__ float ws[4];
  if ((threadIdx.x & 63) == 0) ws[threadIdx.x >> 6] = s;
  __syncthreads();
  if (threadIdx.x == 0)
    atomicAdd(out, (ws[0] + ws[1] + ws[2] + ws[3]) * (1.0f / N_TOT));
}

// ---- launcher --------------------------------------------------------------
extern "C" void kernel_launch(void* const* d_in, const int* in_sizes, int n_in,
                              void* d_out, int out_size, void* d_ws, size_t ws_size,
                              hipStream_t stream) {
  const float* X = (const float*)d_in[0];
  float* out = (float*)d_out;

  float* tsum = (float*)d_ws;                       // 8192 fp32 = 32 KB
  u8* Xn = (u8*)d_ws + 65536;                       // 8192x512 fp8 = 4 MB

  normalize_kernel<<<N_TOT / 4, 256, 0, stream>>>(X, Xn, tsum, out);
  gemm_exp_rowsum<<<NTRI, 256, 0, stream>>>(Xn, tsum);
  finalize_kernel<<<N_TOT / 256, 256, 0, stream>>>(tsum, out);
}